// Round 7
// baseline (326.665 us; speedup 1.0000x reference)
//
#include <hip/hip_runtime.h>
#include <hip/hip_bf16.h>

#define GCN_N 100000
#define GB1 1563   // ceil(100000 / 64) gemm blocks (64 rows each)

typedef unsigned short u16;
typedef unsigned int u32;
typedef unsigned char u8;
typedef float f32x4 __attribute__((ext_vector_type(4)));
typedef short bf16x8 __attribute__((ext_vector_type(8)));

union v16 { uint4 u; bf16x8 h; };

// ---- bf16 helpers (manual, RNE) ----
__device__ inline u16 f2bf(float f) {
    u32 u = __float_as_uint(f);
    return (u16)((u + 0x7fffu + ((u >> 16) & 1u)) >> 16);
}
__device__ inline u32 pack2(float a, float b) {
    return (u32)f2bf(a) | ((u32)f2bf(b) << 16);
}
__device__ inline float bf_lo(u32 u) { return __uint_as_float(u << 16); }
__device__ inline float bf_hi(u32 u) { return __uint_as_float(u & 0xffff0000u); }

__device__ inline void addu8(float* a, float4 v) {
    u32 u;
    u = __float_as_uint(v.x); a[0] += bf_lo(u); a[1] += bf_hi(u);
    u = __float_as_uint(v.y); a[2] += bf_lo(u); a[3] += bf_hi(u);
    u = __float_as_uint(v.z); a[4] += bf_lo(u); a[5] += bf_hi(u);
    u = __float_as_uint(v.w); a[6] += bf_lo(u); a[7] += bf_hi(u);
}
__device__ inline void setu8(float* a, float4 v) {
    u32 u;
    u = __float_as_uint(v.x); a[0] = bf_lo(u); a[1] = bf_hi(u);
    u = __float_as_uint(v.y); a[2] = bf_lo(u); a[3] = bf_hi(u);
    u = __float_as_uint(v.z); a[4] = bf_lo(u); a[5] = bf_hi(u);
    u = __float_as_uint(v.w); a[6] = bf_lo(u); a[7] = bf_hi(u);
}

// MFMA via the gfx950 builtin.
__device__ inline void mfma16(f32x4& d, uint4 a, uint4 b) {
    v16 av, bv; av.u = a; bv.u = b;
    d = __builtin_amdgcn_mfma_f32_16x16x32_bf16(av.h, bv.h, d, 0, 0, 0);
}

// ---------------- CSR build ----------------

// 8 edges/thread: 8 independent atomic chains in flight; rank packed u8.
__global__ __launch_bounds__(256) void k_rank(const int* __restrict__ dst,
                                              int* __restrict__ cnt,
                                              u8* __restrict__ rank, int E) {
    long long base = ((long long)blockIdx.x * 256 + threadIdx.x) * 8;
    if (base + 8 <= E) {
        int4 d0 = *(const int4*)(dst + base);
        int4 d1 = *(const int4*)(dst + base + 4);
        u32 r0 = (u32)atomicAdd(&cnt[d0.x], 1) & 0xffu;
        u32 r1 = (u32)atomicAdd(&cnt[d0.y], 1) & 0xffu;
        u32 r2 = (u32)atomicAdd(&cnt[d0.z], 1) & 0xffu;
        u32 r3 = (u32)atomicAdd(&cnt[d0.w], 1) & 0xffu;
        u32 r4 = (u32)atomicAdd(&cnt[d1.x], 1) & 0xffu;
        u32 r5 = (u32)atomicAdd(&cnt[d1.y], 1) & 0xffu;
        u32 r6 = (u32)atomicAdd(&cnt[d1.z], 1) & 0xffu;
        u32 r7 = (u32)atomicAdd(&cnt[d1.w], 1) & 0xffu;
        uint2 w;
        w.x = r0 | (r1 << 8) | (r2 << 16) | (r3 << 24);
        w.y = r4 | (r5 << 8) | (r6 << 16) | (r7 << 24);
        *(uint2*)(rank + base) = w;
    } else {
        for (long long i = base; i < E; ++i)
            rank[i] = (u8)atomicAdd(&cnt[dst[i]], 1);
    }
}

__global__ __launch_bounds__(256) void k_bsum(const int* __restrict__ cnt,
                                              int* __restrict__ bsum, int n) {
    int i = blockIdx.x * 256 + threadIdx.x;
    int v = (i < n) ? cnt[i] : 0;
    #pragma unroll
    for (int off = 32; off > 0; off >>= 1) v += __shfl_down(v, off, 64);
    __shared__ int ws[4];
    const int lane = threadIdx.x & 63, wid = threadIdx.x >> 6;
    if (lane == 0) ws[wid] = v;
    __syncthreads();
    if (threadIdx.x == 0) bsum[blockIdx.x] = ws[0] + ws[1] + ws[2] + ws[3];
}

__global__ __launch_bounds__(512) void k_bscan(const int* __restrict__ bsum,
                                               int* __restrict__ bbase,
                                               int* __restrict__ rowstart,
                                               int nb, int n) {
    __shared__ int wsum[8];
    __shared__ int woff[8];
    __shared__ int total;
    const int lane = threadIdx.x & 63, wid = threadIdx.x >> 6;
    int v = (threadIdx.x < nb) ? bsum[threadIdx.x] : 0;
    int s = v;
    #pragma unroll
    for (int off = 1; off < 64; off <<= 1) {
        int t = __shfl_up(s, off, 64);
        if (lane >= off) s += t;
    }
    if (lane == 63) wsum[wid] = s;
    __syncthreads();
    if (threadIdx.x == 0) {
        int run = 0;
        #pragma unroll
        for (int w = 0; w < 8; ++w) { int t = wsum[w]; woff[w] = run; run += t; }
        total = run;
    }
    __syncthreads();
    if (threadIdx.x < nb) bbase[threadIdx.x] = woff[wid] + (s - v);
    if (threadIdx.x == 0) rowstart[n] = total;
}

__global__ __launch_bounds__(256) void k_rows(const int* __restrict__ cnt,
                                              const int* __restrict__ bbase,
                                              int* __restrict__ rowstart,
                                              float* __restrict__ dinv, int n) {
    __shared__ int wsum[4];
    __shared__ int woff[4];
    const int lane = threadIdx.x & 63, wid = threadIdx.x >> 6;
    int i = blockIdx.x * 256 + threadIdx.x;
    int v = (i < n) ? cnt[i] : 0;
    int s = v;
    #pragma unroll
    for (int off = 1; off < 64; off <<= 1) {
        int t = __shfl_up(s, off, 64);
        if (lane >= off) s += t;
    }
    if (lane == 63) wsum[wid] = s;
    __syncthreads();
    if (threadIdx.x == 0) {
        int run = bbase[blockIdx.x];
        #pragma unroll
        for (int w = 0; w < 4; ++w) { int t = wsum[w]; woff[w] = run; run += t; }
    }
    __syncthreads();
    if (i < n) {
        rowstart[i] = woff[wid] + (s - v);
        dinv[i] = rsqrtf((float)(v + 1));   // +1 self-loop
    }
}

// ---------------- W -> Wt bf16 transposed [n][k] (once, tiny) ----------------
__global__ __launch_bounds__(256) void k_wprep(const float* __restrict__ W1,
                                               const float* __restrict__ W2,
                                               u16* __restrict__ Wt1,
                                               u16* __restrict__ Wt2) {
    const float* W = blockIdx.x ? W2 : W1;
    u16* Wt = blockIdx.x ? Wt2 : Wt1;
    for (int i = threadIdx.x; i < 16384; i += 256) {
        int k = i >> 7, nn = i & 127;
        Wt[nn * 128 + k] = f2bf(W[i]);
    }
}

// ---------------- MFMA GEMM core: 64 rows x 128 cols, K=128 ----------------
__device__ __attribute__((always_inline))
inline void gemm_core(const uint4* Xs, const u16* __restrict__ Wt,
                      const float* __restrict__ dinv, u16* __restrict__ H,
                      long long row0, int n) {
    const int t = threadIdx.x;
    const int wid = t >> 6;
    const int l = t & 63, lm = l & 15, lh = l >> 4;
    uint4 a[4];
    const int lrow = wid * 16 + lm;
    #pragma unroll
    for (int kk = 0; kk < 4; ++kk) {
        int byte = (lrow * 256 + kk * 64 + lh * 16) ^ ((lm & 7) << 4);
        a[kk] = Xs[byte >> 4];
    }
    const uint4* wb = (const uint4*)Wt;
    f32x4 acc[8];
    #pragma unroll
    for (int j = 0; j < 8; ++j) acc[j] = (f32x4){0.f, 0.f, 0.f, 0.f};
    #pragma unroll
    for (int j = 0; j < 8; ++j) {
        #pragma unroll
        for (int kk = 0; kk < 4; ++kk) {
            uint4 b = wb[(j * 16 + lm) * 16 + kk * 4 + lh];
            mfma16(acc[j], a[kk], b);
        }
    }
    long long gr0 = row0 + wid * 16 + lh * 4;
    float dv[4];
    #pragma unroll
    for (int r = 0; r < 4; ++r) dv[r] = (gr0 + r < n) ? dinv[gr0 + r] : 0.f;
    #pragma unroll
    for (int j = 0; j < 8; ++j) {
        #pragma unroll
        for (int r = 0; r < 4; ++r) {
            long long grow = gr0 + r;
            if (grow < n) H[grow * 128 + j * 16 + lm] = f2bf(acc[j][r] * dv[r]);
        }
    }
}

// ---------------- fused: MFMA GEMM1 + batched atomic-free CSR scatter --------
__global__ __launch_bounds__(256) void k_gemm1_scatter(
        const float* __restrict__ X, const u16* __restrict__ Wt,
        const float* __restrict__ dinv, u16* __restrict__ H,
        const int* __restrict__ src, const int* __restrict__ dst,
        const u8* __restrict__ rank, const int* __restrict__ rowstart,
        int* __restrict__ csr_src, int E, int n) {
    __shared__ uint4 Xs[1024];   // 16 KB
    if (blockIdx.x >= GB1) {
        // 8 edges/thread: 8 independent rowstart gathers + stores in flight
        long long base = ((long long)(blockIdx.x - GB1) * 256 + threadIdx.x) * 8;
        if (base + 8 <= E) {
            int4 d0 = *(const int4*)(dst + base);
            int4 d1 = *(const int4*)(dst + base + 4);
            int4 s0 = *(const int4*)(src + base);
            int4 s1 = *(const int4*)(src + base + 4);
            uint2 rr = *(const uint2*)(rank + base);
            int p0 = rowstart[d0.x] + (int)( rr.x        & 0xffu);
            int p1 = rowstart[d0.y] + (int)((rr.x >>  8) & 0xffu);
            int p2 = rowstart[d0.z] + (int)((rr.x >> 16) & 0xffu);
            int p3 = rowstart[d0.w] + (int)((rr.x >> 24) & 0xffu);
            int p4 = rowstart[d1.x] + (int)( rr.y        & 0xffu);
            int p5 = rowstart[d1.y] + (int)((rr.y >>  8) & 0xffu);
            int p6 = rowstart[d1.z] + (int)((rr.y >> 16) & 0xffu);
            int p7 = rowstart[d1.w] + (int)((rr.y >> 24) & 0xffu);
            csr_src[p0] = s0.x; csr_src[p1] = s0.y;
            csr_src[p2] = s0.z; csr_src[p3] = s0.w;
            csr_src[p4] = s1.x; csr_src[p5] = s1.y;
            csr_src[p6] = s1.z; csr_src[p7] = s1.w;
        } else {
            for (long long i = base; i < E; ++i)
                csr_src[rowstart[dst[i]] + rank[i]] = src[i];
        }
        return;
    }
    const long long row0 = (long long)blockIdx.x * 64;
    const int t = threadIdx.x;
    uint2* Xs2 = (uint2*)Xs;
    #pragma unroll
    for (int i = 0; i < 8; ++i) {
        int idx = i * 1024 + t * 4;
        int row = idx >> 7, k = idx & 127;
        long long grow = row0 + row; if (grow >= n) grow = n - 1;
        float4 v = *(const float4*)(X + grow * 128 + k);
        int byte = (row * 256 + k * 2) ^ ((row & 7) << 4);
        uint2 p; p.x = pack2(v.x, v.y); p.y = pack2(v.z, v.w);
        Xs2[byte >> 3] = p;
    }
    __syncthreads();
    gemm_core(Xs, Wt, dinv, H, row0, n);
}

// ---------------- MFMA GEMM2 (bf16 -> bf16) ----------------
__global__ __launch_bounds__(256) void k_gemm2(
        const u16* __restrict__ X, const u16* __restrict__ Wt,
        const float* __restrict__ dinv, u16* __restrict__ H, int n) {
    __shared__ uint4 Xs[1024];   // 16 KB
    const long long row0 = (long long)blockIdx.x * 64;
    const int t = threadIdx.x;
    #pragma unroll
    for (int i = 0; i < 4; ++i) {
        int idx = i * 2048 + t * 8;
        int row = idx >> 7, k = idx & 127;
        long long grow = row0 + row; if (grow >= n) grow = n - 1;
        uint4 v = *(const uint4*)(X + grow * 128 + k);
        int byte = (row * 256 + k * 2) ^ ((row & 7) << 4);
        Xs[byte >> 4] = v;
    }
    __syncthreads();
    gemm_core(Xs, Wt, dinv, H, row0, n);
}

// ---------------- aggregate (bf16 rows), 8-deep gather pipeline --------------
template<int OUT_BF16>
__global__ __launch_bounds__(256) void k_agg(const u16* __restrict__ h,
                                             const int* __restrict__ rowstart,
                                             const int* __restrict__ csr_src,
                                             const float* __restrict__ dinv,
                                             const float* __restrict__ bias,
                                             void* __restrict__ outp, int n) {
    const int q    = threadIdx.x >> 4;   // node slot in block
    const int sub  = threadIdx.x & 15;   // channel group (8 bf16)
    const int node = blockIdx.x * 16 + q;
    if (node >= n) return;
    const float di = dinv[node];
    int e = rowstart[node];
    const int end = rowstart[node + 1];
    const float4* __restrict__ hv = (const float4*)h;   // 16 x 16B per row
    float a[8], b[8];
    setu8(a, hv[(size_t)node * 16 + sub]);              // self (pre-scaled)
    #pragma unroll
    for (int j = 0; j < 8; ++j) b[j] = 0.f;
    for (; e + 8 <= end; e += 8) {
        int s0 = csr_src[e + 0], s1 = csr_src[e + 1];
        int s2 = csr_src[e + 2], s3 = csr_src[e + 3];
        int s4 = csr_src[e + 4], s5 = csr_src[e + 5];
        int s6 = csr_src[e + 6], s7 = csr_src[e + 7];
        float4 v0 = hv[(size_t)s0 * 16 + sub];
        float4 v1 = hv[(size_t)s1 * 16 + sub];
        float4 v2 = hv[(size_t)s2 * 16 + sub];
        float4 v3 = hv[(size_t)s3 * 16 + sub];
        float4 v4 = hv[(size_t)s4 * 16 + sub];
        float4 v5 = hv[(size_t)s5 * 16 + sub];
        float4 v6 = hv[(size_t)s6 * 16 + sub];
        float4 v7 = hv[(size_t)s7 * 16 + sub];
        addu8(a, v0); addu8(b, v1); addu8(a, v2); addu8(b, v3);
        addu8(a, v4); addu8(b, v5); addu8(a, v6); addu8(b, v7);
    }
    for (; e + 4 <= end; e += 4) {
        int s0 = csr_src[e + 0], s1 = csr_src[e + 1];
        int s2 = csr_src[e + 2], s3 = csr_src[e + 3];
        float4 v0 = hv[(size_t)s0 * 16 + sub];
        float4 v1 = hv[(size_t)s1 * 16 + sub];
        float4 v2 = hv[(size_t)s2 * 16 + sub];
        float4 v3 = hv[(size_t)s3 * 16 + sub];
        addu8(a, v0); addu8(b, v1); addu8(a, v2); addu8(b, v3);
    }
    for (; e < end; ++e) {
        float4 v = hv[(size_t)csr_src[e] * 16 + sub];
        addu8(a, v);
    }
    const float4 bv0 = ((const float4*)bias)[sub * 2];
    const float4 bv1 = ((const float4*)bias)[sub * 2 + 1];
    float o[8];
    o[0] = fmaxf(fmaf(a[0] + b[0], di, bv0.x), 0.f);
    o[1] = fmaxf(fmaf(a[1] + b[1], di, bv0.y), 0.f);
    o[2] = fmaxf(fmaf(a[2] + b[2], di, bv0.z), 0.f);
    o[3] = fmaxf(fmaf(a[3] + b[3], di, bv0.w), 0.f);
    o[4] = fmaxf(fmaf(a[4] + b[4], di, bv1.x), 0.f);
    o[5] = fmaxf(fmaf(a[5] + b[5], di, bv1.y), 0.f);
    o[6] = fmaxf(fmaf(a[6] + b[6], di, bv1.z), 0.f);
    o[7] = fmaxf(fmaf(a[7] + b[7], di, bv1.w), 0.f);
    if (OUT_BF16) {
        float4 pv;
        pv.x = __uint_as_float(pack2(o[0], o[1]));
        pv.y = __uint_as_float(pack2(o[2], o[3]));
        pv.z = __uint_as_float(pack2(o[4], o[5]));
        pv.w = __uint_as_float(pack2(o[6], o[7]));
        ((float4*)outp)[(size_t)node * 16 + sub] = pv;
    } else {
        float* out = (float*)outp + (size_t)node * 128 + sub * 8;
        float4 w0 = {o[0], o[1], o[2], o[3]};
        float4 w1 = {o[4], o[5], o[6], o[7]};
        *(float4*)(out + 0) = w0;
        *(float4*)(out + 4) = w1;
    }
}

// ---------------- launch ----------------

extern "C" void kernel_launch(void* const* d_in, const int* in_sizes, int n_in,
                              void* d_out, int out_size, void* d_ws, size_t ws_size,
                              hipStream_t stream) {
    const float* x   = (const float*)d_in[0];
    const int* edges = (const int*)d_in[1];
    const float* W1  = (const float*)d_in[2];
    const float* b1  = (const float*)d_in[3];
    const float* W2  = (const float*)d_in[4];
    const float* b2  = (const float*)d_in[5];
    const int E = in_sizes[1] / 2;
    const int N = GCN_N;
    const int* srcp = edges;
    const int* dstp = edges + E;
    const int NB  = (N + 255) / 256;           // 391
    const int EB8 = (E + 2047) / 2048;         // 782 (8 edges/thread)

    char* ws = (char*)d_ws;
    int*   cnt      = (int*)(ws + 0);          // 400 KB
    int*   rowstart = (int*)(ws + 524288);     // 400 KB + 4
    float* dinvp    = (float*)(ws + 1048576);  // 400 KB
    int*   bsum     = (int*)(ws + 1474560);
    int*   bbase    = (int*)(ws + 1507328);
    u16*   wt1      = (u16*)(ws + 1572864);    // 32 KB
    u16*   wt2      = (u16*)(ws + 1605632);    // 32 KB
    int*   csr      = (int*)(ws + 2097152);    // 6.4 MB
    u8*    rank     = (u8*)(ws + 8912896);     // 1.6 MB
    u16*   h1       = (u16*)(ws + 16777216);   // 25.6 MB bf16
    u16*   h2       = (u16*)(ws + 44040192);   // 25.6 MB bf16 (end ~69.6 MB)

    hipMemsetAsync(cnt, 0, N * sizeof(int), stream);

    k_rank <<<EB8, 256, 0, stream>>>(dstp, cnt, rank, E);
    k_bsum <<<NB, 256, 0, stream>>>(cnt, bsum, N);
    k_bscan<<<1, 512, 0, stream>>>(bsum, bbase, rowstart, NB, N);
    k_rows <<<NB, 256, 0, stream>>>(cnt, bbase, rowstart, dinvp, N);
    k_wprep<<<2, 256, 0, stream>>>(W1, W2, wt1, wt2);

    // layer 1 MFMA GEMM fused with batched atomic-free CSR scatter
    k_gemm1_scatter<<<GB1 + EB8, 256, 0, stream>>>(
        x, wt1, dinvp, h1, srcp, dstp, rank, rowstart, csr, E, N);
    k_agg<1><<<(N + 15) / 16, 256, 0, stream>>>(h1, rowstart, csr, dinvp, b1, h2, N);
    // layer 2
    k_gemm2<<<GB1, 256, 0, stream>>>(h2, wt2, dinvp, h1, N);
    k_agg<0><<<(N + 15) / 16, 256, 0, stream>>>(h1, rowstart, csr, dinvp, b2, d_out, N);
}